// Round 12
// baseline (44.043 us; speedup 1.0000x reference)
//
#include <hip/hip_runtime.h>
#include <hip/hip_bf16.h>

typedef __attribute__((ext_vector_type(8))) short bf16x8;
typedef __attribute__((ext_vector_type(4))) float f32x4;

#define NPIX 32768

// ws byte layout:
//   [0, 32768)      W1fT bf16 [64 d][256 c]   (BN scale folded)
//   [32768, 51200)  W2T  bf16 [144 e][64 d]
//   [51200, 51456)  b1f  f32  [64]            (BN-folded bias)

__device__ __forceinline__ ushort f2bf(float f) {
    __hip_bfloat16 h = __float2bfloat16(f);   // single v_cvt, RNE
    ushort u; __builtin_memcpy(&u, &h, 2);
    return u;
}

__global__ __launch_bounds__(256) void fold_kernel(
        const float* __restrict__ W1, const float* __restrict__ b1,
        const float* __restrict__ gamma, const float* __restrict__ beta,
        const float* __restrict__ mean, const float* __restrict__ var,
        const float* __restrict__ W2, void* __restrict__ ws) {
    ushort* w1t = (ushort*)ws;
    ushort* w2t = (ushort*)ws + 16384;
    float*  b1f = (float*)((char*)ws + 51200);
    int tid = blockIdx.x * 256 + threadIdx.x;
    if (tid < 16384) {
        int d = tid >> 8, c = tid & 255;
        float scale = gamma[d] * rsqrtf(var[d] + 1e-3f);
        w1t[tid] = f2bf(W1[c * 64 + d] * scale);       // W1fT[d][c]
    }
    if (tid < 9216) {
        int e = tid >> 6, d = tid & 63;
        w2t[tid] = f2bf(W2[d * 144 + e]);              // W2T[e][d]
    }
    if (tid < 64) {
        float scale = gamma[tid] * rsqrtf(var[tid] + 1e-3f);
        b1f[tid] = (b1[tid] - mean[tid]) * scale + beta[tid];
    }
}

// Fully fused, ZERO barriers, wave-private LDS arenas.
// ROUND-12 CHANGE vs round 9: 8 px per wave (was 16) -> 4096 waves total
// = 16 waves/CU (was 8): doubles latency-hiding concurrency, which round
// 8's counters showed is the binding limit (occ 17.6%, all pipes <12%).
// MFMA stays 16x16: A-rows 8..15 duplicate rows 0..7 via r16&7 remap
// (MfmaUtil ~1% => wasted half-tile is free); only q<8 results stored.
// Arena 5120 B/wave:
//   phase A: xs bf16 [8 rows][512 B] @0, XOR-swizzled (x tile)
//   phase B: hs bf16 [8 rows][128 B] @4096, swizzled (relu(h))
//   phase C: ks f32  [8 rows][148]   @0 (4736 B; aliases xs + hs row tail --
//            safe: ds ops of one wave complete in order; all xs/hs reads
//            are issued before the first ks write)
// Block = 32 px (half image row), 4 waves, grid 1024 = 4 blocks/CU.
// Weights from global (L2/L1-hot). XCD k owns image k (b = xcd).
__global__ __launch_bounds__(256, 4) void fused_kernel(
        const float* __restrict__ x, const void* __restrict__ ws,
        const float* __restrict__ b2, float* __restrict__ ker,
        float* __restrict__ out) {
    __shared__ __align__(16) char smem[20480];
    const int t = threadIdx.x;
    const int wv = t >> 6, ln = t & 63;
    char* arena = smem + wv * 5120;
    const int bid = (int)blockIdx.x;
    const int xcd = bid & 7;                 // image index (B == 8 XCDs)
    const int idx = bid >> 3;                // [0,128): half-row within image
    const int row = idx >> 1, half = idx & 1;
    const int lb  = xcd * 64 + row;          // b*64 + i
    const int pw  = lb * 64 + half * 32 + wv * 8;   // wave's first pixel
    const int j0  = half * 32 + wv * 8;             // wave's first column
    const ushort* w1t = (const ushort*)ws;
    const ushort* w2t = (const ushort*)ws + 16384;
    const float*  b1f = (const float*)((const char*)ws + 51200);
    const int r16 = ln & 15, g = ln >> 4;
    const int q8 = r16 & 7;                  // A-row remap (dup rows 8..15)

    // ---- stage wave's 8 x-rows: f32 -> bf16, XOR-swizzled ----
    {
        const float4* xg = (const float4*)(x + (size_t)pw * 256);
        #pragma unroll
        for (int it = 0; it < 8; it++) {
            float4 v = xg[it * 64 + ln];
            ushort4 b4; b4.x = f2bf(v.x); b4.y = f2bf(v.y);
            b4.z = f2bf(v.z); b4.w = f2bf(v.w);
            int bcol = (ln * 8) ^ (it << 4);
            *(ushort4*)(arena + it * 512 + bcol) = b4;
        }
    }

    // ---- GEMM1: 8 px x 64 d; A from arena xs (row q8), B from global ----
    f32x4 acc[4];
    #pragma unroll
    for (int dt = 0; dt < 4; dt++) {
        float bv = b1f[dt * 16 + r16];
        acc[dt] = (f32x4){bv, bv, bv, bv};
    }
    #pragma unroll
    for (int kk = 0; kk < 8; kk++) {
        int bcA = (kk * 64 + g * 16) ^ (q8 << 4);
        bf16x8 av = *(const bf16x8*)(arena + q8 * 512 + bcA);
        #pragma unroll
        for (int dt = 0; dt < 4; dt++) {
            bf16x8 bv = *(const bf16x8*)(w1t + (dt * 16 + r16) * 256 + kk * 32 + g * 8);
            acc[dt] = __builtin_amdgcn_mfma_f32_16x16x32_bf16(av, bv, acc[dt], 0, 0, 0);
        }
    }

    // relu -> bf16 -> hs (arena+4096, rows 0..7, swizzled); q>=8 discarded
    #pragma unroll
    for (int dt = 0; dt < 4; dt++) {
        #pragma unroll
        for (int r = 0; r < 4; r++) {
            int q = g * 4 + r;                        // C/D row
            if (q < 8) {
                int bcol = ((dt * 16 + r16) * 2) ^ (q << 4);
                *(ushort*)(arena + 4096 + q * 128 + bcol) = f2bf(fmaxf(acc[dt][r], 0.f));
            }
        }
    }

    // ---- GEMM2: 8 px x 144 e; A from hs (row q8), B from global W2T ----
    f32x4 acc2[9];
    #pragma unroll
    for (int et = 0; et < 9; et++) {
        float bv = b2[et * 16 + r16];
        acc2[et] = (f32x4){bv, bv, bv, bv};
    }
    #pragma unroll
    for (int kk = 0; kk < 2; kk++) {
        int bcA = (kk * 64 + g * 16) ^ (q8 << 4);
        bf16x8 av = *(const bf16x8*)(arena + 4096 + q8 * 128 + bcA);
        #pragma unroll
        for (int et = 0; et < 9; et++) {
            bf16x8 bv = *(const bf16x8*)(w2t + (et * 16 + r16) * 64 + kk * 32 + g * 8);
            acc2[et] = __builtin_amdgcn_mfma_f32_16x16x32_bf16(av, bv, acc2[et], 0, 0, 0);
        }
    }

    // ---- ker: NT store to global + f32 ks in wave arena (aliases xs/hs) ----
    float* ksf = (float*)arena;                       // [8][148]
    #pragma unroll
    for (int et = 0; et < 9; et++) {
        #pragma unroll
        for (int r = 0; r < 4; r++) {
            int q = g * 4 + r;
            if (q < 8) {
                int e = et * 16 + r16;
                float v = acc2[et][r];
                __builtin_nontemporal_store(v, &ker[(size_t)(pw + q) * 144 + e]);
                ksf[q * 148 + e] = v;
            }
        }
    }

    // ---- involution: shift-register 3x3 window; ks from LDS ----
    const int i  = lb & 63;
    const int s4 = (ln & 3) * 4;
    const f32x4* xv4 = (const f32x4*)x;
    const f32x4 z4 = {0.f, 0.f, 0.f, 0.f};

    f32x4 wmL[3], wmC[3], wmN[3];
    #pragma unroll
    for (int r = 0; r < 3; r++) {
        int rw = i + r - 1;
        bool rv = (unsigned)rw < 64u;
        wmL[r] = (rv && j0 > 0)
            ? xv4[(size_t)((lb + r - 1) * 64 + (j0 - 1)) * 64 + ln] : z4;
        wmC[r] = rv
            ? xv4[(size_t)((lb + r - 1) * 64 + j0) * 64 + ln] : z4;
    }
    #pragma unroll
    for (int pp = 0; pp < 8; pp++) {
        const int j = j0 + pp;
        const bool cv = (j + 1) < 64;
        #pragma unroll
        for (int r = 0; r < 3; r++) {
            int rw = i + r - 1;
            bool rv = (unsigned)rw < 64u;
            wmN[r] = (rv && cv)
                ? xv4[(size_t)((lb + r - 1) * 64 + (j + 1)) * 64 + ln] : z4;
        }
        const float* kp = ksf + pp * 148 + s4;
        f32x4 o = {0.f, 0.f, 0.f, 0.f};
        #pragma unroll
        for (int r = 0; r < 3; r++) {
            o += (*(const f32x4*)(kp + (r * 3 + 0) * 16)) * wmL[r];
            o += (*(const f32x4*)(kp + (r * 3 + 1) * 16)) * wmC[r];
            o += (*(const f32x4*)(kp + (r * 3 + 2) * 16)) * wmN[r];
        }
        __builtin_nontemporal_store(o, &((f32x4*)out)[(size_t)(pw + pp) * 64 + ln]);
        #pragma unroll
        for (int r = 0; r < 3; r++) { wmL[r] = wmC[r]; wmC[r] = wmN[r]; }
    }
}

extern "C" void kernel_launch(void* const* d_in, const int* in_sizes, int n_in,
                              void* d_out, int out_size, void* d_ws, size_t ws_size,
                              hipStream_t stream) {
    const float* x     = (const float*)d_in[0];
    const float* W1    = (const float*)d_in[1];
    const float* b1    = (const float*)d_in[2];
    const float* gamma = (const float*)d_in[3];
    const float* beta  = (const float*)d_in[4];
    const float* mmean = (const float*)d_in[5];
    const float* mvar  = (const float*)d_in[6];
    const float* W2    = (const float*)d_in[7];
    const float* b2    = (const float*)d_in[8];

    float* out_main = (float*)d_out;                 // (B,H,W,C)   = 8388608 f32
    float* out_ker  = (float*)d_out + 8388608;       // (B,H,W,144) = 4718592 f32

    fold_kernel<<<64, 256, 0, stream>>>(W1, b1, gamma, beta, mmean, mvar, W2, d_ws);
    fused_kernel<<<NPIX / 32, 256, 0, stream>>>(x, d_ws, b2, out_ker, out_main);
}

// Round 13
// 36.441 us; speedup vs baseline: 1.2086x; 1.2086x over previous
//
#include <hip/hip_runtime.h>
#include <hip/hip_bf16.h>

typedef __attribute__((ext_vector_type(8))) short bf16x8;
typedef __attribute__((ext_vector_type(4))) float f32x4;

#define NPIX 32768

// ws byte layout:
//   [0, 32768)      W1fT bf16 [64 d][256 c]   (BN scale folded)
//   [32768, 51200)  W2T  bf16 [144 e][64 d]
//   [51200, 51456)  b1f  f32  [64]            (BN-folded bias)

__device__ __forceinline__ ushort f2bf(float f) {
    __hip_bfloat16 h = __float2bfloat16(f);   // single v_cvt, RNE
    ushort u; __builtin_memcpy(&u, &h, 2);
    return u;
}

__global__ __launch_bounds__(256) void fold_kernel(
        const float* __restrict__ W1, const float* __restrict__ b1,
        const float* __restrict__ gamma, const float* __restrict__ beta,
        const float* __restrict__ mean, const float* __restrict__ var,
        const float* __restrict__ W2, void* __restrict__ ws) {
    ushort* w1t = (ushort*)ws;
    ushort* w2t = (ushort*)ws + 16384;
    float*  b1f = (float*)((char*)ws + 51200);
    int tid = blockIdx.x * 256 + threadIdx.x;
    if (tid < 16384) {
        int d = tid >> 8, c = tid & 255;
        float scale = gamma[d] * rsqrtf(var[d] + 1e-3f);
        w1t[tid] = f2bf(W1[c * 64 + d] * scale);       // W1fT[d][c]
    }
    if (tid < 9216) {
        int e = tid >> 6, d = tid & 63;
        w2t[tid] = f2bf(W2[d * 144 + e]);              // W2T[e][d]
    }
    if (tid < 64) {
        float scale = gamma[tid] * rsqrtf(var[tid] + 1e-3f);
        b1f[tid] = (b1[tid] - mean[tid]) * scale + beta[tid];
    }
}

// R9 structure (best: 36.2 us) + ONE change: ker global stores sunk to the
// kernel END so the involution's x loads never wait (in-order vmcnt) behind
// 36 scattered NT stores. acc2 stays live through invol (~+36 VGPR; ~100
// total, fits easily under the (256,2) cap of 256 -- grid 512 = 2 blocks/CU
// is grid-limited anyway, so relaxing from 4 to 2 costs nothing).
// Fully fused, ZERO barriers, wave-private LDS arenas (10240 B per wave):
//   phase A: xs bf16 [16 rows][512 B] @arena+0, swizzled   (x tile)
//   phase B: hs bf16 [16 rows][128 B] @arena+8192, swizzled (relu(h))
//   phase C: ks f32  [16 rows][148]   @arena+0 (9472 B; aliases xs+hs --
//            safe: written after all xs/hs LDS reads, per-wave in-order)
// Block = 1 image row (64 px), 4 waves, wave owns 16 px end-to-end.
// Weights from global (L2-hot). XCD k owns image k for halo L2 locality.
__global__ __launch_bounds__(256, 2) void fused_kernel(
        const float* __restrict__ x, const void* __restrict__ ws,
        const float* __restrict__ b2, float* __restrict__ ker,
        float* __restrict__ out) {
    __shared__ __align__(16) char smem[40960];
    const int t = threadIdx.x;
    const int wv = t >> 6, ln = t & 63;
    char* arena = smem + wv * 10240;
    const int bid = (int)blockIdx.x;
    const int lb = (bid & 7) * 64 + (bid >> 3);  // XCD k <- image k
    const int p0 = lb * 64;
    const ushort* w1t = (const ushort*)ws;
    const ushort* w2t = (const ushort*)ws + 16384;
    const float*  b1f = (const float*)((const char*)ws + 51200);
    const int r16 = ln & 15, g = ln >> 4;

    // ---- stage wave's 16 x-rows: f32 -> bf16, XOR-swizzled, local rows ----
    {
        const float4* xg = (const float4*)(x + (size_t)(p0 + wv * 16) * 256);
        #pragma unroll
        for (int it = 0; it < 16; it++) {
            float4 v = xg[it * 64 + ln];
            ushort4 b4; b4.x = f2bf(v.x); b4.y = f2bf(v.y);
            b4.z = f2bf(v.z); b4.w = f2bf(v.w);
            int bcol = (ln * 8) ^ ((it & 7) << 4);
            *(ushort4*)(arena + it * 512 + bcol) = b4;
        }
    }

    // ---- GEMM1: 16 px x 64 d; A from arena xs, B from global W1fT ----
    f32x4 acc[4];
    #pragma unroll
    for (int dt = 0; dt < 4; dt++) {
        float bv = b1f[dt * 16 + r16];
        acc[dt] = (f32x4){bv, bv, bv, bv};
    }
    #pragma unroll
    for (int kk = 0; kk < 8; kk++) {
        int bcA = (kk * 64 + g * 16) ^ ((r16 & 7) << 4);
        bf16x8 av = *(const bf16x8*)(arena + r16 * 512 + bcA);
        #pragma unroll
        for (int dt = 0; dt < 4; dt++) {
            bf16x8 bv = *(const bf16x8*)(w1t + (dt * 16 + r16) * 256 + kk * 32 + g * 8);
            acc[dt] = __builtin_amdgcn_mfma_f32_16x16x32_bf16(av, bv, acc[dt], 0, 0, 0);
        }
    }

    // relu -> bf16 -> hs (arena+8192, local rows 0..15, swizzled)
    #pragma unroll
    for (int dt = 0; dt < 4; dt++) {
        #pragma unroll
        for (int r = 0; r < 4; r++) {
            int q = g * 4 + r;                        // local px (C/D row)
            int bcol = ((dt * 16 + r16) * 2) ^ ((q & 7) << 4);
            *(ushort*)(arena + 8192 + q * 128 + bcol) = f2bf(fmaxf(acc[dt][r], 0.f));
        }
    }

    // ---- GEMM2: 16 px x 144 e; A from hs, B from global W2T ----
    f32x4 acc2[9];
    #pragma unroll
    for (int et = 0; et < 9; et++) {
        float bv = b2[et * 16 + r16];
        acc2[et] = (f32x4){bv, bv, bv, bv};
    }
    #pragma unroll
    for (int kk = 0; kk < 2; kk++) {
        int bcA = (kk * 64 + g * 16) ^ ((r16 & 7) << 4);
        bf16x8 av = *(const bf16x8*)(arena + 8192 + r16 * 128 + bcA);
        #pragma unroll
        for (int et = 0; et < 9; et++) {
            bf16x8 bv = *(const bf16x8*)(w2t + (et * 16 + r16) * 64 + kk * 32 + g * 8);
            acc2[et] = __builtin_amdgcn_mfma_f32_16x16x32_bf16(av, bv, acc2[et], 0, 0, 0);
        }
    }

    // ---- ks: f32 transpose into wave arena (LDS only; ker stores deferred) ----
    float* ksf = (float*)arena;                       // [16][148]
    #pragma unroll
    for (int et = 0; et < 9; et++) {
        #pragma unroll
        for (int r = 0; r < 4; r++) {
            int q = g * 4 + r;
            ksf[q * 148 + et * 16 + r16] = acc2[et][r];
        }
    }

    // ---- involution: shift-register 3x3 window; ks from LDS ----
    const int i  = lb & 63;
    const int s4 = (ln & 3) * 4;
    const f32x4* xv4 = (const f32x4*)x;
    const int j0 = wv * 16;
    const f32x4 z4 = {0.f, 0.f, 0.f, 0.f};

    f32x4 wmL[3], wmC[3], wmN[3];
    #pragma unroll
    for (int r = 0; r < 3; r++) {
        int row = i + r - 1;
        bool rv = (unsigned)row < 64u;
        wmL[r] = (rv && j0 > 0)
            ? xv4[(size_t)((lb + r - 1) * 64 + (j0 - 1)) * 64 + ln] : z4;
        wmC[r] = rv
            ? xv4[(size_t)((lb + r - 1) * 64 + j0) * 64 + ln] : z4;
    }
    #pragma unroll 4
    for (int pp = 0; pp < 16; pp++) {
        const int j = j0 + pp;
        const bool cv = (j + 1) < 64;
        #pragma unroll
        for (int r = 0; r < 3; r++) {
            int row = i + r - 1;
            bool rv = (unsigned)row < 64u;
            wmN[r] = (rv && cv)
                ? xv4[(size_t)((lb + r - 1) * 64 + (j + 1)) * 64 + ln] : z4;
        }
        const float* kp = ksf + pp * 148 + s4;
        f32x4 o = {0.f, 0.f, 0.f, 0.f};
        #pragma unroll
        for (int r = 0; r < 3; r++) {
            o += (*(const f32x4*)(kp + (r * 3 + 0) * 16)) * wmL[r];
            o += (*(const f32x4*)(kp + (r * 3 + 1) * 16)) * wmC[r];
            o += (*(const f32x4*)(kp + (r * 3 + 2) * 16)) * wmN[r];
        }
        __builtin_nontemporal_store(o, &((f32x4*)out)[(size_t)(p0 + j) * 64 + ln]);
        #pragma unroll
        for (int r = 0; r < 3; r++) { wmL[r] = wmC[r]; wmC[r] = wmN[r]; }
    }

    // ---- terminal ker stores: no later loads -> no vmcnt drain on the path ----
    #pragma unroll
    for (int et = 0; et < 9; et++) {
        #pragma unroll
        for (int r = 0; r < 4; r++) {
            int q = g * 4 + r;
            __builtin_nontemporal_store(acc2[et][r],
                &ker[(size_t)(p0 + wv * 16 + q) * 144 + et * 16 + r16]);
        }
    }
}

extern "C" void kernel_launch(void* const* d_in, const int* in_sizes, int n_in,
                              void* d_out, int out_size, void* d_ws, size_t ws_size,
                              hipStream_t stream) {
    const float* x     = (const float*)d_in[0];
    const float* W1    = (const float*)d_in[1];
    const float* b1    = (const float*)d_in[2];
    const float* gamma = (const float*)d_in[3];
    const float* beta  = (const float*)d_in[4];
    const float* mmean = (const float*)d_in[5];
    const float* mvar  = (const float*)d_in[6];
    const float* W2    = (const float*)d_in[7];
    const float* b2    = (const float*)d_in[8];

    float* out_main = (float*)d_out;                 // (B,H,W,C)   = 8388608 f32
    float* out_ker  = (float*)d_out + 8388608;       // (B,H,W,144) = 4718592 f32

    fold_kernel<<<64, 256, 0, stream>>>(W1, b1, gamma, beta, mmean, mvar, W2, d_ws);
    fused_kernel<<<NPIX / 64, 256, 0, stream>>>(x, d_ws, b2, out_ker, out_main);
}

// Round 14
// 36.217 us; speedup vs baseline: 1.2161x; 1.0062x over previous
//
#include <hip/hip_runtime.h>
#include <hip/hip_bf16.h>

typedef __attribute__((ext_vector_type(8))) short bf16x8;
typedef __attribute__((ext_vector_type(4))) float f32x4;

#define NPIX 32768

// ws byte layout:
//   [0, 32768)      W1fT bf16 [64 d][256 c]   (BN scale folded)
//   [32768, 51200)  W2T  bf16 [144 e][64 d]
//   [51200, 51456)  b1f  f32  [64]            (BN-folded bias)

__device__ __forceinline__ ushort f2bf(float f) {
    __hip_bfloat16 h = __float2bfloat16(f);   // single v_cvt, RNE
    ushort u; __builtin_memcpy(&u, &h, 2);
    return u;
}

__global__ __launch_bounds__(256) void fold_kernel(
        const float* __restrict__ W1, const float* __restrict__ b1,
        const float* __restrict__ gamma, const float* __restrict__ beta,
        const float* __restrict__ mean, const float* __restrict__ var,
        const float* __restrict__ W2, void* __restrict__ ws) {
    ushort* w1t = (ushort*)ws;
    ushort* w2t = (ushort*)ws + 16384;
    float*  b1f = (float*)((char*)ws + 51200);
    int tid = blockIdx.x * 256 + threadIdx.x;
    if (tid < 16384) {
        int d = tid >> 8, c = tid & 255;
        float scale = gamma[d] * rsqrtf(var[d] + 1e-3f);
        w1t[tid] = f2bf(W1[c * 64 + d] * scale);       // W1fT[d][c]
    }
    if (tid < 9216) {
        int e = tid >> 6, d = tid & 63;
        w2t[tid] = f2bf(W2[d * 144 + e]);              // W2T[e][d]
    }
    if (tid < 64) {
        float scale = gamma[tid] * rsqrtf(var[tid] + 1e-3f);
        b1f[tid] = (b1[tid] - mean[tid]) * scale + beta[tid];
    }
}

// R13 structure (zero barriers, wave-private arenas) + two latency cuts:
//  (a) invol window preload (wmL/wmC + first wmN) hoisted ABOVE GEMM2, so
//      its L2/HBM latency hides under GEMM2 + ks transpose;
//  (b) coalesced ker epilogue: re-read ksf from LDS (9 x ds_read_b128 with
//      fidx=m*64+ln, row=fidx/36) and NT-store 9 x 1KB contiguous chunks
//      per wave -- replaces 36 scattered 4B-per-lane stores, and lets acc2
//      die right after the ks transpose (lower register pressure).
// Wave-private LDS arenas (10240 B per wave):
//   phase A: xs bf16 [16 rows][512 B] @arena+0, swizzled   (x tile)
//   phase B: hs bf16 [16 rows][128 B] @arena+8192, swizzled (relu(h))
//   phase C: ks f32  [16 rows][148]   @arena+0 (9472 B; aliases xs+hs --
//            safe: written after all xs/hs LDS reads, per-wave in-order)
// Block = 1 image row (64 px), 4 waves, wave owns 16 px end-to-end.
// Weights from global (L2-hot). XCD k owns image k for halo L2 locality.
__global__ __launch_bounds__(256, 2) void fused_kernel(
        const float* __restrict__ x, const void* __restrict__ ws,
        const float* __restrict__ b2, float* __restrict__ ker,
        float* __restrict__ out) {
    __shared__ __align__(16) char smem[40960];
    const int t = threadIdx.x;
    const int wv = t >> 6, ln = t & 63;
    char* arena = smem + wv * 10240;
    const int bid = (int)blockIdx.x;
    const int lb = (bid & 7) * 64 + (bid >> 3);  // XCD k <- image k
    const int p0 = lb * 64;
    const ushort* w1t = (const ushort*)ws;
    const ushort* w2t = (const ushort*)ws + 16384;
    const float*  b1f = (const float*)((const char*)ws + 51200);
    const int r16 = ln & 15, g = ln >> 4;

    // ---- stage wave's 16 x-rows: f32 -> bf16, XOR-swizzled, local rows ----
    {
        const float4* xg = (const float4*)(x + (size_t)(p0 + wv * 16) * 256);
        #pragma unroll
        for (int it = 0; it < 16; it++) {
            float4 v = xg[it * 64 + ln];
            ushort4 b4; b4.x = f2bf(v.x); b4.y = f2bf(v.y);
            b4.z = f2bf(v.z); b4.w = f2bf(v.w);
            int bcol = (ln * 8) ^ ((it & 7) << 4);
            *(ushort4*)(arena + it * 512 + bcol) = b4;
        }
    }

    // ---- GEMM1: 16 px x 64 d; A from arena xs, B from global W1fT ----
    f32x4 acc[4];
    #pragma unroll
    for (int dt = 0; dt < 4; dt++) {
        float bv = b1f[dt * 16 + r16];
        acc[dt] = (f32x4){bv, bv, bv, bv};
    }
    #pragma unroll
    for (int kk = 0; kk < 8; kk++) {
        int bcA = (kk * 64 + g * 16) ^ ((r16 & 7) << 4);
        bf16x8 av = *(const bf16x8*)(arena + r16 * 512 + bcA);
        #pragma unroll
        for (int dt = 0; dt < 4; dt++) {
            bf16x8 bv = *(const bf16x8*)(w1t + (dt * 16 + r16) * 256 + kk * 32 + g * 8);
            acc[dt] = __builtin_amdgcn_mfma_f32_16x16x32_bf16(av, bv, acc[dt], 0, 0, 0);
        }
    }

    // relu -> bf16 -> hs (arena+8192, local rows 0..15, swizzled)
    #pragma unroll
    for (int dt = 0; dt < 4; dt++) {
        #pragma unroll
        for (int r = 0; r < 4; r++) {
            int q = g * 4 + r;                        // local px (C/D row)
            int bcol = ((dt * 16 + r16) * 2) ^ ((q & 7) << 4);
            *(ushort*)(arena + 8192 + q * 128 + bcol) = f2bf(fmaxf(acc[dt][r], 0.f));
        }
    }

    // ---- invol window preload: depends only on x; latency hides under GEMM2 ----
    const int i  = lb & 63;
    const f32x4* xv4 = (const f32x4*)x;
    const int j0 = wv * 16;
    const f32x4 z4 = {0.f, 0.f, 0.f, 0.f};
    f32x4 wmL[3], wmC[3], wmN[3];
    #pragma unroll
    for (int r = 0; r < 3; r++) {
        int row = i + r - 1;
        bool rv = (unsigned)row < 64u;
        wmL[r] = (rv && j0 > 0)
            ? xv4[(size_t)((lb + r - 1) * 64 + (j0 - 1)) * 64 + ln] : z4;
        wmC[r] = rv
            ? xv4[(size_t)((lb + r - 1) * 64 + j0) * 64 + ln] : z4;
        wmN[r] = rv
            ? xv4[(size_t)((lb + r - 1) * 64 + (j0 + 1)) * 64 + ln] : z4;  // j0+1<64 always (j0<=48)
    }

    // ---- GEMM2: 16 px x 144 e; A from hs, B from global W2T ----
    f32x4 acc2[9];
    #pragma unroll
    for (int et = 0; et < 9; et++) {
        float bv = b2[et * 16 + r16];
        acc2[et] = (f32x4){bv, bv, bv, bv};
    }
    #pragma unroll
    for (int kk = 0; kk < 2; kk++) {
        int bcA = (kk * 64 + g * 16) ^ ((r16 & 7) << 4);
        bf16x8 av = *(const bf16x8*)(arena + 8192 + r16 * 128 + bcA);
        #pragma unroll
        for (int et = 0; et < 9; et++) {
            bf16x8 bv = *(const bf16x8*)(w2t + (et * 16 + r16) * 64 + kk * 32 + g * 8);
            acc2[et] = __builtin_amdgcn_mfma_f32_16x16x32_bf16(av, bv, acc2[et], 0, 0, 0);
        }
    }

    // ---- ks: f32 transpose into wave arena (LDS only); acc2 dies here ----
    float* ksf = (float*)arena;                       // [16][148]
    #pragma unroll
    for (int et = 0; et < 9; et++) {
        #pragma unroll
        for (int r = 0; r < 4; r++) {
            int q = g * 4 + r;
            ksf[q * 148 + et * 16 + r16] = acc2[et][r];
        }
    }

    // ---- involution: shift-register 3x3 window; ks from LDS ----
    const int s4 = (ln & 3) * 4;
    #pragma unroll 4
    for (int pp = 0; pp < 16; pp++) {
        const int j = j0 + pp;
        const float* kp = ksf + pp * 148 + s4;
        f32x4 o = {0.f, 0.f, 0.f, 0.f};
        #pragma unroll
        for (int r = 0; r < 3; r++) {
            o += (*(const f32x4*)(kp + (r * 3 + 0) * 16)) * wmL[r];
            o += (*(const f32x4*)(kp + (r * 3 + 1) * 16)) * wmC[r];
            o += (*(const f32x4*)(kp + (r * 3 + 2) * 16)) * wmN[r];
        }
        __builtin_nontemporal_store(o, &((f32x4*)out)[(size_t)(p0 + j) * 64 + ln]);
        // shift window and load next column (j+2) for iteration pp+1
        #pragma unroll
        for (int r = 0; r < 3; r++) { wmL[r] = wmC[r]; wmC[r] = wmN[r]; }
        if (pp < 15) {
            const int jn = j + 2;
            const bool cv = jn < 64;
            #pragma unroll
            for (int r = 0; r < 3; r++) {
                int row = i + r - 1;
                bool rv = (unsigned)row < 64u;
                wmN[r] = (rv && cv)
                    ? xv4[(size_t)((lb + r - 1) * 64 + jn) * 64 + ln] : z4;
            }
        }
    }

    // ---- coalesced ker epilogue: ksf -> 9 x 1KB contiguous NT stores ----
    {
        float* kerW = ker + (size_t)(p0 + wv * 16) * 144;   // wave's 2304 floats
        #pragma unroll
        for (int m = 0; m < 9; m++) {
            int fidx = m * 64 + ln;          // f32x4 index within wave region
            int row  = fidx / 36;            // px row 0..15
            int col4 = fidx - row * 36;      // f32x4 within row (144/4=36)
            f32x4 v = *(const f32x4*)(ksf + row * 148 + col4 * 4);
            __builtin_nontemporal_store(v, (f32x4*)(kerW + fidx * 4));
        }
    }
}

extern "C" void kernel_launch(void* const* d_in, const int* in_sizes, int n_in,
                              void* d_out, int out_size, void* d_ws, size_t ws_size,
                              hipStream_t stream) {
    const float* x     = (const float*)d_in[0];
    const float* W1    = (const float*)d_in[1];
    const float* b1    = (const float*)d_in[2];
    const float* gamma = (const float*)d_in[3];
    const float* beta  = (const float*)d_in[4];
    const float* mmean = (const float*)d_in[5];
    const float* mvar  = (const float*)d_in[6];
    const float* W2    = (const float*)d_in[7];
    const float* b2    = (const float*)d_in[8];

    float* out_main = (float*)d_out;                 // (B,H,W,C)   = 8388608 f32
    float* out_ker  = (float*)d_out + 8388608;       // (B,H,W,144) = 4718592 f32

    fold_kernel<<<64, 256, 0, stream>>>(W1, b1, gamma, beta, mmean, mvar, W2, d_ws);
    fused_kernel<<<NPIX / 64, 256, 0, stream>>>(x, d_ws, b2, out_ker, out_main);
}

// Round 15
// 27.688 us; speedup vs baseline: 1.5907x; 1.3081x over previous
//
#include <hip/hip_runtime.h>
#include <hip/hip_bf16.h>

typedef __attribute__((ext_vector_type(8))) short bf16x8;
typedef __attribute__((ext_vector_type(4))) float f32x4;

#define NPIX 32768

// ws byte layout (fragment-order packed weights):
//   [0, 32768)      W1p bf16: elem ((kk*4+dt)*64+ln)*8+cc  (kk<8, dt<4)
//                   = W1fT[d=dt*16+(ln&15)][c=kk*32+((ln>>4)&3)*8+cc] * bnscale
//   [32768, 51200)  W2p bf16: elem ((kk*9+et)*64+ln)*8+cc  (kk<2, et<9)
//                   = W2T[e=et*16+(ln&15)][d=kk*32+((ln>>4)&3)*8+cc]
//   [51200, 51456)  b1f f32 [64]  (BN-folded bias)
// -> every MFMA B-fragment load is ONE coalesced 1KB wave access at a
//    wave-uniform base (identical across waves; L1-resident).

__device__ __forceinline__ ushort f2bf(float f) {
    __hip_bfloat16 h = __float2bfloat16(f);   // single v_cvt, RNE
    ushort u; __builtin_memcpy(&u, &h, 2);
    return u;
}

__global__ __launch_bounds__(256) void fold_kernel(
        const float* __restrict__ W1, const float* __restrict__ b1,
        const float* __restrict__ gamma, const float* __restrict__ beta,
        const float* __restrict__ mean, const float* __restrict__ var,
        const float* __restrict__ W2, void* __restrict__ ws) {
    ushort* w1p = (ushort*)ws;
    ushort* w2p = (ushort*)ws + 16384;
    float*  b1f = (float*)((char*)ws + 51200);
    int tid = blockIdx.x * 256 + threadIdx.x;
    if (tid < 16384) {
        int cc = tid & 7, ln = (tid >> 3) & 63, dt = (tid >> 9) & 3, kk = tid >> 11;
        int d = dt * 16 + (ln & 15);
        int c = kk * 32 + ((ln >> 4) & 3) * 8 + cc;
        float scale = gamma[d] * rsqrtf(var[d] + 1e-3f);
        w1p[tid] = f2bf(W1[c * 64 + d] * scale);
    }
    if (tid < 9216) {
        int cc = tid & 7, ln = (tid >> 3) & 63, rem = tid >> 9;  // rem<18
        int et = rem % 9, kk = rem / 9;
        int e = et * 16 + (ln & 15);
        int dcol = kk * 32 + ((ln >> 4) & 3) * 8 + cc;
        w2p[tid] = f2bf(W2[dcol * 144 + e]);
    }
    if (tid < 64) {
        float scale = gamma[tid] * rsqrtf(var[tid] + 1e-3f);
        b1f[tid] = (b1[tid] - mean[tid]) * scale + beta[tid];
    }
}

// R14 structure (zero barriers, wave-private arenas, coalesced ker epilogue)
// + (1) fragment-order weight loads (coalesced 1KB, wave-uniform base),
// + (2) invol shift-register with PREFETCH DEPTH 2 (4-column window).
// Wave-private LDS arenas (10240 B per wave):
//   phase A: xs bf16 [16 rows][512 B] @arena+0, swizzled   (x tile)
//   phase B: hs bf16 [16 rows][128 B] @arena+8192, swizzled (relu(h))
//   phase C: ks f32  [16 rows][148]   @arena+0 (aliases xs+hs -- safe:
//            written after all xs/hs LDS reads, per-wave in-order)
// Block = 1 image row (64 px), 4 waves, wave owns 16 px end-to-end.
// XCD k owns image k for halo L2 locality.
__global__ __launch_bounds__(256, 2) void fused_kernel(
        const float* __restrict__ x, const void* __restrict__ ws,
        const float* __restrict__ b2, float* __restrict__ ker,
        float* __restrict__ out) {
    __shared__ __align__(16) char smem[40960];
    const int t = threadIdx.x;
    const int wv = t >> 6, ln = t & 63;
    char* arena = smem + wv * 10240;
    const int bid = (int)blockIdx.x;
    const int lb = (bid & 7) * 64 + (bid >> 3);  // XCD k <- image k
    const int p0 = lb * 64;
    const ushort* w1p = (const ushort*)ws;
    const ushort* w2p = (const ushort*)ws + 16384;
    const float*  b1f = (const float*)((const char*)ws + 51200);
    const int r16 = ln & 15, g = ln >> 4;

    // ---- stage wave's 16 x-rows: f32 -> bf16, XOR-swizzled, local rows ----
    {
        const float4* xg = (const float4*)(x + (size_t)(p0 + wv * 16) * 256);
        #pragma unroll
        for (int it = 0; it < 16; it++) {
            float4 v = xg[it * 64 + ln];
            ushort4 b4; b4.x = f2bf(v.x); b4.y = f2bf(v.y);
            b4.z = f2bf(v.z); b4.w = f2bf(v.w);
            int bcol = (ln * 8) ^ ((it & 7) << 4);
            *(ushort4*)(arena + it * 512 + bcol) = b4;
        }
    }

    // ---- GEMM1: 16 px x 64 d; A from arena xs, B coalesced from W1p ----
    f32x4 acc[4];
    #pragma unroll
    for (int dt = 0; dt < 4; dt++) {
        float bv = b1f[dt * 16 + r16];
        acc[dt] = (f32x4){bv, bv, bv, bv};
    }
    #pragma unroll
    for (int kk = 0; kk < 8; kk++) {
        int bcA = (kk * 64 + g * 16) ^ ((r16 & 7) << 4);
        bf16x8 av = *(const bf16x8*)(arena + r16 * 512 + bcA);
        #pragma unroll
        for (int dt = 0; dt < 4; dt++) {
            bf16x8 bv = *(const bf16x8*)(w1p + (((kk * 4 + dt) << 6) + ln) * 8);
            acc[dt] = __builtin_amdgcn_mfma_f32_16x16x32_bf16(av, bv, acc[dt], 0, 0, 0);
        }
    }

    // relu -> bf16 -> hs (arena+8192, local rows 0..15, swizzled)
    #pragma unroll
    for (int dt = 0; dt < 4; dt++) {
        #pragma unroll
        for (int r = 0; r < 4; r++) {
            int q = g * 4 + r;                        // local px (C/D row)
            int bcol = ((dt * 16 + r16) * 2) ^ ((q & 7) << 4);
            *(ushort*)(arena + 8192 + q * 128 + bcol) = f2bf(fmaxf(acc[dt][r], 0.f));
        }
    }

    // ---- GEMM2: 16 px x 144 e; A from hs, B coalesced from W2p ----
    f32x4 acc2[9];
    #pragma unroll
    for (int et = 0; et < 9; et++) {
        float bv = b2[et * 16 + r16];
        acc2[et] = (f32x4){bv, bv, bv, bv};
    }
    #pragma unroll
    for (int kk = 0; kk < 2; kk++) {
        int bcA = (kk * 64 + g * 16) ^ ((r16 & 7) << 4);
        bf16x8 av = *(const bf16x8*)(arena + 8192 + r16 * 128 + bcA);
        #pragma unroll
        for (int et = 0; et < 9; et++) {
            bf16x8 bv = *(const bf16x8*)(w2p + (((kk * 9 + et) << 6) + ln) * 8);
            acc2[et] = __builtin_amdgcn_mfma_f32_16x16x32_bf16(av, bv, acc2[et], 0, 0, 0);
        }
    }

    // ---- ks: f32 transpose into wave arena (LDS only); acc2 dies here ----
    float* ksf = (float*)arena;                       // [16][148]
    #pragma unroll
    for (int et = 0; et < 9; et++) {
        #pragma unroll
        for (int r = 0; r < 4; r++) {
            int q = g * 4 + r;
            ksf[q * 148 + et * 16 + r16] = acc2[et][r];
        }
    }

    // ---- involution: 4-column shift window, prefetch depth 2 ----
    const int i  = lb & 63;
    const int s4 = (ln & 3) * 4;
    const f32x4* xv4 = (const f32x4*)x;
    const int j0 = wv * 16;
    const f32x4 z4 = {0.f, 0.f, 0.f, 0.f};

    f32x4 wa[3], wb[3], wc[3], wd[3];   // cols j-1, j, j+1, j+2
    #pragma unroll
    for (int r = 0; r < 3; r++) {
        int row = i + r - 1;
        bool rv = (unsigned)row < 64u;
        const size_t rb = (size_t)(lb + r - 1) * 64;
        wa[r] = (rv && j0 > 0) ? xv4[(rb + (j0 - 1)) * 64 + ln] : z4;
        wb[r] = rv ? xv4[(rb + j0) * 64 + ln] : z4;
        wc[r] = rv ? xv4[(rb + j0 + 1) * 64 + ln] : z4;   // j0+1 <= 49 < 64
        wd[r] = rv ? xv4[(rb + j0 + 2) * 64 + ln] : z4;   // j0+2 <= 50 < 64
    }
    #pragma unroll 4
    for (int pp = 0; pp < 16; pp++) {
        const int j = j0 + pp;
        const float* kp = ksf + pp * 148 + s4;
        f32x4 o = {0.f, 0.f, 0.f, 0.f};
        #pragma unroll
        for (int r = 0; r < 3; r++) {
            o += (*(const f32x4*)(kp + (r * 3 + 0) * 16)) * wa[r];
            o += (*(const f32x4*)(kp + (r * 3 + 1) * 16)) * wb[r];
            o += (*(const f32x4*)(kp + (r * 3 + 2) * 16)) * wc[r];
        }
        __builtin_nontemporal_store(o, &((f32x4*)out)[(size_t)(p0 + j) * 64 + ln]);
        #pragma unroll
        for (int r = 0; r < 3; r++) { wa[r] = wb[r]; wb[r] = wc[r]; wc[r] = wd[r]; }
        if (pp < 14) {
            const int jn = j + 3;                      // consumed at pp+2
            const bool cv = jn < 64;
            #pragma unroll
            for (int r = 0; r < 3; r++) {
                int row = i + r - 1;
                bool rv = (unsigned)row < 64u;
                wd[r] = (rv && cv)
                    ? xv4[((size_t)(lb + r - 1) * 64 + jn) * 64 + ln] : z4;
            }
        }
    }

    // ---- coalesced ker epilogue: ksf -> 9 x 1KB contiguous NT stores ----
    {
        float* kerW = ker + (size_t)(p0 + wv * 16) * 144;   // wave's 2304 floats
        #pragma unroll
        for (int m = 0; m < 9; m++) {
            int fidx = m * 64 + ln;          // f32x4 index within wave region
            int row  = fidx / 36;            // px row 0..15
            int col4 = fidx - row * 36;      // f32x4 within row (144/4=36)
            f32x4 v = *(const f32x4*)(ksf + row * 148 + col4 * 4);
            __builtin_nontemporal_store(v, (f32x4*)(kerW + fidx * 4));
        }
    }
}

extern "C" void kernel_launch(void* const* d_in, const int* in_sizes, int n_in,
                              void* d_out, int out_size, void* d_ws, size_t ws_size,
                              hipStream_t stream) {
    const float* x     = (const float*)d_in[0];
    const float* W1    = (const float*)d_in[1];
    const float* b1    = (const float*)d_in[2];
    const float* gamma = (const float*)d_in[3];
    const float* beta  = (const float*)d_in[4];
    const float* mmean = (const float*)d_in[5];
    const float* mvar  = (const float*)d_in[6];
    const float* W2    = (const float*)d_in[7];
    const float* b2    = (const float*)d_in[8];

    float* out_main = (float*)d_out;                 // (B,H,W,C)   = 8388608 f32
    float* out_ker  = (float*)d_out + 8388608;       // (B,H,W,144) = 4718592 f32

    fold_kernel<<<64, 256, 0, stream>>>(W1, b1, gamma, beta, mmean, mvar, W2, d_ws);
    fused_kernel<<<NPIX / 64, 256, 0, stream>>>(x, d_ws, b2, out_ker, out_main);
}